// Round 1
// baseline (192.444 us; speedup 1.0000x reference)
//
#include <hip/hip_runtime.h>
#include <hip/hip_bf16.h>

typedef __attribute__((ext_vector_type(8))) short short8;
typedef __attribute__((ext_vector_type(4))) float f32x4;

#define DFEAT 128

__device__ __forceinline__ unsigned short f2bf(float f) {
    unsigned int u = __float_as_uint(f);
    u += 0x7FFFu + ((u >> 16) & 1u);   // round-nearest-even
    return (unsigned short)(u >> 16);
}
__device__ __forceinline__ float bf2f(unsigned int bits) {
    return __uint_as_float(bits << 16);
}

// Phase 1: A[n][:] = zi[n] @ W1[0:128][:] + b1   (table 0)
//          B[n][:] = zj[n] @ W1[128:256][:]      (table 1)
// stored as bf16. One wave computes a 16-row x 128-col strip via mfma 16x16x32.
__global__ __launch_bounds__(256) void node_gemm(
    const float* __restrict__ zi, const float* __restrict__ zj,
    const float* __restrict__ W1, const float* __restrict__ b1,
    unsigned short* __restrict__ Aout, unsigned short* __restrict__ Bout,
    int nN)
{
    __shared__ unsigned short Wt[128][136];   // Wt[col][k], +8 pad: 2-way-free banks
    const int table = blockIdx.y;
    const float* __restrict__ z = table ? zj : zi;
    unsigned short* __restrict__ outp = table ? Bout : Aout;

    // stage W-half transposed as bf16 (coalesced global read)
    for (int idx = threadIdx.x; idx < 128 * 128; idx += 256) {
        int c = idx & 127, k = idx >> 7;
        Wt[c][k] = f2bf(W1[(size_t)(table * 128 + k) * 128 + c]);
    }
    __syncthreads();

    const int lane = threadIdx.x & 63;
    const int l15  = lane & 15;
    const int kg   = lane >> 4;          // 0..3
    int wv = blockIdx.x * 4 + (threadIdx.x >> 6);
    int nw = gridDim.x * 4;
    int nStrips = (nN + 15) >> 4;

    for (int strip = wv; strip < nStrips; strip += nw) {
        int row = strip * 16 + l15;
        const float* zr = z + (size_t)(row < nN ? row : nN - 1) * DFEAT + kg * 8;

        f32x4 acc[8];
#pragma unroll
        for (int ct = 0; ct < 8; ++ct) acc[ct] = (f32x4){0.f, 0.f, 0.f, 0.f};

#pragma unroll
        for (int kk = 0; kk < 4; ++kk) {
            float4 f0 = *(const float4*)(zr + kk * 32);
            float4 f1 = *(const float4*)(zr + kk * 32 + 4);
            short8 a;
            a[0] = (short)f2bf(f0.x); a[1] = (short)f2bf(f0.y);
            a[2] = (short)f2bf(f0.z); a[3] = (short)f2bf(f0.w);
            a[4] = (short)f2bf(f1.x); a[5] = (short)f2bf(f1.y);
            a[6] = (short)f2bf(f1.z); a[7] = (short)f2bf(f1.w);
#pragma unroll
            for (int ct = 0; ct < 8; ++ct) {
                short8 b = *(const short8*)(&Wt[ct * 16 + l15][kk * 32 + kg * 8]);
                acc[ct] = __builtin_amdgcn_mfma_f32_16x16x32_bf16(a, b, acc[ct], 0, 0, 0);
            }
        }
        // C/D layout: col = lane&15, row = (lane>>4)*4 + j  [m89]
#pragma unroll
        for (int ct = 0; ct < 8; ++ct) {
            int col = ct * 16 + l15;
            float bias = table ? 0.f : b1[col];
#pragma unroll
            for (int j = 0; j < 4; ++j) {
                int rc = strip * 16 + kg * 4 + j;
                if (rc < nN) outp[(size_t)rc * DFEAT + col] = f2bf(acc[ct][j] + bias);
            }
        }
    }
}

// Phase 2: per edge (one wave): out = sigmoid(relu(A[src]+B[dst]) . W3 + b3)
__global__ __launch_bounds__(256) void edge_kernel(
    const unsigned short* __restrict__ A, const unsigned short* __restrict__ B,
    const int* __restrict__ src, const int* __restrict__ dst,
    const float* __restrict__ W3, const float* __restrict__ b3,
    float* __restrict__ out, int nE)
{
    const int lane = threadIdx.x & 63;
    const float w3a = W3[lane * 2];
    const float w3b = W3[lane * 2 + 1];
    const float bb  = b3[0];
    int wv = blockIdx.x * 4 + (threadIdx.x >> 6);
    int nw = gridDim.x * 4;
    for (int e = wv; e < nE; e += nw) {
        int s = src[e], d = dst[e];
        unsigned int av = *(const unsigned int*)(A + (size_t)s * DFEAT + lane * 2);
        unsigned int bv = *(const unsigned int*)(B + (size_t)d * DFEAT + lane * 2);
        float h0 = bf2f(av & 0xFFFFu) + bf2f(bv & 0xFFFFu);
        float h1 = bf2f(av >> 16)     + bf2f(bv >> 16);
        h0 = fmaxf(h0, 0.f); h1 = fmaxf(h1, 0.f);
        float p = fmaf(h0, w3a, h1 * w3b);
#pragma unroll
        for (int off = 32; off > 0; off >>= 1) p += __shfl_xor(p, off, 64);
        if (lane == 0) out[e] = 1.f / (1.f + __expf(-(p + bb)));
    }
}

// Fallback (only if d_ws too small): direct per-edge dense compute. Slow, correct.
__global__ __launch_bounds__(256) void fallback_kernel(
    const float* __restrict__ zi, const float* __restrict__ zj,
    const int* __restrict__ src, const int* __restrict__ dst,
    const float* __restrict__ W1, const float* __restrict__ b1,
    const float* __restrict__ W3, const float* __restrict__ b3,
    float* __restrict__ out, int nE)
{
    int e = blockIdx.x * blockDim.x + threadIdx.x;
    if (e >= nE) return;
    const float* a = zi + (size_t)src[e] * DFEAT;
    const float* b = zj + (size_t)dst[e] * DFEAT;
    float logit = b3[0];
    for (int h = 0; h < 128; ++h) {
        float acc = b1[h];
        for (int k = 0; k < 128; ++k) acc = fmaf(a[k], W1[(size_t)k * 128 + h], acc);
        for (int k = 0; k < 128; ++k) acc = fmaf(b[k], W1[(size_t)(128 + k) * 128 + h], acc);
        if (acc > 0.f) logit = fmaf(acc, W3[h], logit);
    }
    out[e] = 1.f / (1.f + __expf(-logit));
}

extern "C" void kernel_launch(void* const* d_in, const int* in_sizes, int n_in,
                              void* d_out, int out_size, void* d_ws, size_t ws_size,
                              hipStream_t stream) {
    const float* zi = (const float*)d_in[0];
    const float* zj = (const float*)d_in[1];
    const int*  src = (const int*)d_in[2];
    const int*  dst = (const int*)d_in[3];
    const float* W1 = (const float*)d_in[4];
    const float* b1 = (const float*)d_in[5];
    const float* W3 = (const float*)d_in[6];
    const float* b3 = (const float*)d_in[7];
    float* out = (float*)d_out;

    int nN = in_sizes[0] / DFEAT;
    int nE = in_sizes[2];
    size_t abytes = (size_t)nN * DFEAT * sizeof(unsigned short);

    if (ws_size >= 2 * abytes) {
        unsigned short* A = (unsigned short*)d_ws;
        unsigned short* B = A + (size_t)nN * DFEAT;
        dim3 g1(512, 2, 1);
        node_gemm<<<g1, 256, 0, stream>>>(zi, zj, W1, b1, A, B, nN);
        edge_kernel<<<1024, 256, 0, stream>>>(A, B, src, dst, W3, b3, out, nE);
    } else {
        fallback_kernel<<<(nE + 255) / 256, 256, 0, stream>>>(
            zi, zj, src, dst, W1, b1, W3, b3, out, nE);
    }
}

// Round 2
// 104.612 us; speedup vs baseline: 1.8396x; 1.8396x over previous
//
#include <hip/hip_runtime.h>
#include <hip/hip_bf16.h>

typedef __attribute__((ext_vector_type(8))) short short8;
typedef __attribute__((ext_vector_type(4))) float f32x4;
typedef __attribute__((ext_vector_type(4))) unsigned int u32x4;

#define DFEAT 128

__device__ __forceinline__ unsigned short f2bf(float f) {
    unsigned int u = __float_as_uint(f);
    u += 0x7FFFu + ((u >> 16) & 1u);   // round-nearest-even
    return (unsigned short)(u >> 16);
}
__device__ __forceinline__ float bf2f(unsigned int bits) {
    return __uint_as_float(bits << 16);
}

// Phase 1: A[n][:] = zi[n] @ W1[0:128][:] + b1   (table 0)
//          B[n][:] = zj[n] @ W1[128:256][:]      (table 1)
// stored as bf16. One wave computes a 16-row x 128-col strip via mfma 16x16x32.
__global__ __launch_bounds__(256) void node_gemm(
    const float* __restrict__ zi, const float* __restrict__ zj,
    const float* __restrict__ W1, const float* __restrict__ b1,
    unsigned short* __restrict__ Aout, unsigned short* __restrict__ Bout,
    int nN)
{
    __shared__ unsigned short Wt[128][136];   // Wt[col][k]
    const int table = blockIdx.y;
    const float* __restrict__ z = table ? zj : zi;
    unsigned short* __restrict__ outp = table ? Bout : Aout;

    // stage W-half transposed as bf16 (coalesced global read)
    for (int idx = threadIdx.x; idx < 128 * 128; idx += 256) {
        int c = idx & 127, k = idx >> 7;
        Wt[c][k] = f2bf(W1[(size_t)(table * 128 + k) * 128 + c]);
    }
    __syncthreads();

    const int lane = threadIdx.x & 63;
    const int l15  = lane & 15;
    const int kg   = lane >> 4;          // 0..3
    int wv = blockIdx.x * 4 + (threadIdx.x >> 6);
    int nw = gridDim.x * 4;
    int nStrips = (nN + 15) >> 4;

    for (int strip = wv; strip < nStrips; strip += nw) {
        int row = strip * 16 + l15;
        const float* zr = z + (size_t)(row < nN ? row : nN - 1) * DFEAT + kg * 8;

        f32x4 acc[8];
#pragma unroll
        for (int ct = 0; ct < 8; ++ct) acc[ct] = (f32x4){0.f, 0.f, 0.f, 0.f};

#pragma unroll
        for (int kk = 0; kk < 4; ++kk) {
            float4 f0 = *(const float4*)(zr + kk * 32);
            float4 f1 = *(const float4*)(zr + kk * 32 + 4);
            short8 a;
            a[0] = (short)f2bf(f0.x); a[1] = (short)f2bf(f0.y);
            a[2] = (short)f2bf(f0.z); a[3] = (short)f2bf(f0.w);
            a[4] = (short)f2bf(f1.x); a[5] = (short)f2bf(f1.y);
            a[6] = (short)f2bf(f1.z); a[7] = (short)f2bf(f1.w);
#pragma unroll
            for (int ct = 0; ct < 8; ++ct) {
                short8 b = *(const short8*)(&Wt[ct * 16 + l15][kk * 32 + kg * 8]);
                acc[ct] = __builtin_amdgcn_mfma_f32_16x16x32_bf16(a, b, acc[ct], 0, 0, 0);
            }
        }
        // C/D layout: col = lane&15, row = (lane>>4)*4 + j  [m89]
#pragma unroll
        for (int ct = 0; ct < 8; ++ct) {
            int col = ct * 16 + l15;
            float bias = table ? 0.f : b1[col];
#pragma unroll
            for (int j = 0; j < 4; ++j) {
                int rc = strip * 16 + kg * 4 + j;
                if (rc < nN) outp[(size_t)rc * DFEAT + col] = f2bf(acc[ct][j] + bias);
            }
        }
    }
}

// Phase 2: 16 lanes per edge. Lane (sub=lane&15) loads 16B of A[src] and B[dst],
// relu(add), dot with its 8 W3 weights, 4-round shfl_xor reduce within the
// 16-lane group, sub==0 writes sigmoid. 8 edges per wave per iteration (2 quads
// unrolled) -> 16 independent gathers in flight per wave.
__global__ __launch_bounds__(256) void edge_kernel(
    const unsigned short* __restrict__ A, const unsigned short* __restrict__ B,
    const int* __restrict__ src, const int* __restrict__ dst,
    const float* __restrict__ W3, const float* __restrict__ b3,
    float* __restrict__ out, int nE)
{
    const int lane = threadIdx.x & 63;
    const int sub  = lane & 15;     // position within edge group
    const int grp  = lane >> 4;     // which edge of the quad

    float w3v[8];
#pragma unroll
    for (int j = 0; j < 8; ++j) w3v[j] = W3[sub * 8 + j];
    const float bb = b3[0];

    int wv = blockIdx.x * 4 + (threadIdx.x >> 6);
    int nw = gridDim.x * 4;

    for (int base = wv * 8; base < nE; base += nw * 8) {
        int e0 = base + grp;
        int e1 = base + 4 + grp;
        bool v0 = e0 < nE, v1 = e1 < nE;
        int s0 = v0 ? src[e0] : 0, d0 = v0 ? dst[e0] : 0;
        int s1 = v1 ? src[e1] : 0, d1 = v1 ? dst[e1] : 0;

        const u32x4* pa0 = (const u32x4*)(A + (size_t)s0 * DFEAT + sub * 8);
        const u32x4* pb0 = (const u32x4*)(B + (size_t)d0 * DFEAT + sub * 8);
        const u32x4* pa1 = (const u32x4*)(A + (size_t)s1 * DFEAT + sub * 8);
        const u32x4* pb1 = (const u32x4*)(B + (size_t)d1 * DFEAT + sub * 8);
        u32x4 av0 = *pa0, bv0 = *pb0;
        u32x4 av1 = *pa1, bv1 = *pb1;

        float p0 = 0.f, p1 = 0.f;
#pragma unroll
        for (int w = 0; w < 4; ++w) {
            float x0 = fmaxf(bf2f(av0[w] & 0xFFFFu) + bf2f(bv0[w] & 0xFFFFu), 0.f);
            float x1 = fmaxf(bf2f(av0[w] >> 16)     + bf2f(bv0[w] >> 16),     0.f);
            p0 = fmaf(x0, w3v[w * 2], p0);
            p0 = fmaf(x1, w3v[w * 2 + 1], p0);
            float y0 = fmaxf(bf2f(av1[w] & 0xFFFFu) + bf2f(bv1[w] & 0xFFFFu), 0.f);
            float y1 = fmaxf(bf2f(av1[w] >> 16)     + bf2f(bv1[w] >> 16),     0.f);
            p1 = fmaf(y0, w3v[w * 2], p1);
            p1 = fmaf(y1, w3v[w * 2 + 1], p1);
        }
#pragma unroll
        for (int off = 8; off > 0; off >>= 1) {
            p0 += __shfl_xor(p0, off, 64);
            p1 += __shfl_xor(p1, off, 64);
        }
        if (sub == 0) {
            if (v0) out[e0] = 1.f / (1.f + __expf(-(p0 + bb)));
            if (v1) out[e1] = 1.f / (1.f + __expf(-(p1 + bb)));
        }
    }
}

// Fallback (only if d_ws too small): direct per-edge dense compute. Slow, correct.
__global__ __launch_bounds__(256) void fallback_kernel(
    const float* __restrict__ zi, const float* __restrict__ zj,
    const int* __restrict__ src, const int* __restrict__ dst,
    const float* __restrict__ W1, const float* __restrict__ b1,
    const float* __restrict__ W3, const float* __restrict__ b3,
    float* __restrict__ out, int nE)
{
    int e = blockIdx.x * blockDim.x + threadIdx.x;
    if (e >= nE) return;
    const float* a = zi + (size_t)src[e] * DFEAT;
    const float* b = zj + (size_t)dst[e] * DFEAT;
    float logit = b3[0];
    for (int h = 0; h < 128; ++h) {
        float acc = b1[h];
        for (int k = 0; k < 128; ++k) acc = fmaf(a[k], W1[(size_t)k * 128 + h], acc);
        for (int k = 0; k < 128; ++k) acc = fmaf(b[k], W1[(size_t)(128 + k) * 128 + h], acc);
        if (acc > 0.f) logit = fmaf(acc, W3[h], logit);
    }
    out[e] = 1.f / (1.f + __expf(-logit));
}

extern "C" void kernel_launch(void* const* d_in, const int* in_sizes, int n_in,
                              void* d_out, int out_size, void* d_ws, size_t ws_size,
                              hipStream_t stream) {
    const float* zi = (const float*)d_in[0];
    const float* zj = (const float*)d_in[1];
    const int*  src = (const int*)d_in[2];
    const int*  dst = (const int*)d_in[3];
    const float* W1 = (const float*)d_in[4];
    const float* b1 = (const float*)d_in[5];
    const float* W3 = (const float*)d_in[6];
    const float* b3 = (const float*)d_in[7];
    float* out = (float*)d_out;

    int nN = in_sizes[0] / DFEAT;
    int nE = in_sizes[2];
    size_t abytes = (size_t)nN * DFEAT * sizeof(unsigned short);

    if (ws_size >= 2 * abytes) {
        unsigned short* A = (unsigned short*)d_ws;
        unsigned short* B = A + (size_t)nN * DFEAT;
        dim3 g1(512, 2, 1);
        node_gemm<<<g1, 256, 0, stream>>>(zi, zj, W1, b1, A, B, nN);
        edge_kernel<<<2048, 256, 0, stream>>>(A, B, src, dst, W3, b3, out, nE);
    } else {
        fallback_kernel<<<(nE + 255) / 256, 256, 0, stream>>>(
            zi, zj, src, dst, W1, b1, W3, b3, out, nE);
    }
}